// Round 5
// baseline (259.883 us; speedup 1.0000x reference)
//
#include <hip/hip_runtime.h>
#include <hip/hip_bf16.h>

// Problem constants: B=2, S=2048, D=1024, H=16, HD=64
typedef unsigned short u16;
typedef unsigned int u32;
typedef unsigned long long u64;
typedef __attribute__((__ext_vector_type__(8))) short bf16x8;    // 8 bf16 (4 VGPRs)
typedef __attribute__((__ext_vector_type__(4))) float f32x4;     // 16x16 C/D frag
typedef __attribute__((__ext_vector_type__(16))) float f32x16;   // 32x32 C/D frag

__device__ __forceinline__ u16 f2bf(float f) {
    u32 u = __float_as_uint(f);
    return (u16)((u + 0x7fffu + ((u >> 16) & 1u)) >> 16);  // RNE
}

// ---------------------------------------------------------------------------
// Kernel 1: fp32 -> bf16 conversion for x (4M) and W_q/k/v/o (1M each)
// wq/wk/wv land contiguous so the QKV GEMM sees one (3072,1024) B matrix.
// ---------------------------------------------------------------------------
__global__ __launch_bounds__(256) void cvt_kernel(
    const float4* __restrict__ x,  const float4* __restrict__ wq,
    const float4* __restrict__ wk, const float4* __restrict__ wv,
    const float4* __restrict__ wo,
    u16* __restrict__ xb, u16* __restrict__ wqb, u16* __restrict__ wkb,
    u16* __restrict__ wvb, u16* __restrict__ wob)
{
    int gid = blockIdx.x * 256 + threadIdx.x;        // float4 units
    const float4* src; u16* dst; int off;
    if (gid < 1048576) { src = x; dst = xb; off = gid; }
    else {
        int g = gid - 1048576;
        int sel = g >> 18;
        off = g & 262143;
        src = sel == 0 ? wq : sel == 1 ? wk : sel == 2 ? wv : wo;
        dst = sel == 0 ? wqb : sel == 1 ? wkb : sel == 2 ? wvb : wob;
    }
    float4 f = src[off];
    ushort4 o;
    o.x = f2bf(f.x); o.y = f2bf(f.y); o.z = f2bf(f.z); o.w = f2bf(f.w);
    ((ushort4*)dst)[off] = o;
}

// ---------------------------------------------------------------------------
// Kernel 2: pack M into TRANSPOSED bitmask: Mb2[(b*32 + w)*2048 + q] bit i =
// (M[b][q][w*64+i] != 0).  Attn reads 4 consecutive q-rows as one uint4.
// ---------------------------------------------------------------------------
__global__ __launch_bounds__(256) void pack_mask(const int* __restrict__ M,
                                                 u64* __restrict__ Mb2)
{
    int wg   = blockIdx.x * 4 + (threadIdx.x >> 6);  // global wave id
    int lane = threadIdx.x & 63;
    int w = wg & 31;
    int q = (wg >> 5) & 2047;
    int b = wg >> 16;
    size_t base = ((size_t)(b * 2048 + q)) * 2048 + w * 64 + lane;
    u64 bits = __ballot(M[base] != 0);
    if (lane == 0) Mb2[(size_t)(b * 32 + w) * 2048 + q] = bits;
}

// ---------------------------------------------------------------------------
// Kernel 3: GEMM C[m,n] = sum_k A[m,k]*B[n,k] (m97 structure, 128xBN, BK=32).
// MODE 0 (BN=128): fused QKV, B = concat(Wq,Wk,Wv) rows 0..3071.
//   region 0 (n<1024):  Q * 0.125*log2(e) -> Cq [token][1024]
//   region 1: K -> frag-swizzled Kfr (QK B-frag order)
//   region 2: V -> frag-swizzled Vfr (PV B-frag order)
// Frag layout (u16 elems): ((((b*16+h)*32 + kt)*8 + f)*64 + lane)*8 + j
//   Kfr: f = kn*4+t holds K[key=kt*64+kn*32+(lane&31)][d=h*64+t*16+(lane>>5)*8+j]
//   Vfr: f = nd*4+t holds V[key=kt*64+t*16+(lane>>5)*8+j][d=h*64+nd*32+(lane&31)]
// MODE 1 (BN=64): out-projection, fp32 out + bias.
// ---------------------------------------------------------------------------
template<int MODE, int BN>
__global__ __launch_bounds__(256) void gemm_k(
    const u16* __restrict__ Ag, const u16* __restrict__ Bg,
    u16* __restrict__ Cq, u16* __restrict__ Kfr, u16* __restrict__ Vfr,
    float* __restrict__ Cf, const float* __restrict__ bias)
{
    constexpr int Kd = 1024;
    constexpr int NB = BN / 32;              // nb blocks per wave (4 or 2)
    __shared__ u16 As[128 * 32];
    __shared__ u16 Bs[BN * 32];
    const int tid  = threadIdx.x;
    const int wave = tid >> 6, lane = tid & 63;
    const int quad = lane >> 4, l16 = lane & 15;
    const int n0 = blockIdx.x * BN;
    const int m0 = blockIdx.y * 128;

    const int wm = (wave & 1) * 64, wn = (wave >> 1) * (BN / 2);
    f32x4 acc[4][NB];
    #pragma unroll
    for (int i = 0; i < 4; i++)
        #pragma unroll
        for (int j = 0; j < NB; j++)
            acc[i][j] = (f32x4){0.f, 0.f, 0.f, 0.f};

    const int sr = lane >> 2;
    const int sk = (lane & 3) * 8;
    const int ca0 = wave * 2, ca1 = ca0 + 1;
    const u16* gA0 = Ag + (size_t)(m0 + ca0 * 16 + sr) * Kd + sk;
    const u16* gA1 = Ag + (size_t)(m0 + ca1 * 16 + sr) * Kd + sk;
    u16* lA0 = As + ca0 * 512;
    u16* lA1 = As + ca1 * 512;
    const int cb0 = (BN == 128) ? wave * 2 : wave;
    const u16* gB0 = Bg + (size_t)(n0 + cb0 * 16 + sr) * Kd + sk;
    u16* lB0 = Bs + cb0 * 512;
    const u16* gB1 = (BN == 128) ? Bg + (size_t)(n0 + (cb0 + 1) * 16 + sr) * Kd + sk : nullptr;
    u16* lB1 = (BN == 128) ? Bs + (cb0 + 1) * 512 : nullptr;

    #define GLL16(gp, lp) __builtin_amdgcn_global_load_lds( \
        (const __attribute__((address_space(1))) void*)(gp), \
        (__attribute__((address_space(3))) void*)(lp), 16, 0, 0)

    for (int k0 = 0; k0 < Kd; k0 += 32) {
        __syncthreads();
        GLL16(gA0 + k0, lA0);
        GLL16(gA1 + k0, lA1);
        GLL16(gB0 + k0, lB0);
        if (BN == 128) GLL16(gB1 + k0, lB1);
        __syncthreads();

        bf16x8 af[4], bfr[NB];
        #pragma unroll
        for (int mb = 0; mb < 4; mb++)
            af[mb] = *(const bf16x8*)&As[(wm + mb * 16 + l16) * 32 + quad * 8];
        #pragma unroll
        for (int nb = 0; nb < NB; nb++)
            bfr[nb] = *(const bf16x8*)&Bs[(wn + nb * 16 + l16) * 32 + quad * 8];
        #pragma unroll
        for (int mb = 0; mb < 4; mb++)
            #pragma unroll
            for (int nb = 0; nb < NB; nb++)
                acc[mb][nb] = __builtin_amdgcn_mfma_f32_16x16x32_bf16(
                    af[mb], bfr[nb], acc[mb][nb], 0, 0, 0);
    }
    #undef GLL16

    // epilogue: D row = quad*4+r, col = l16
    #pragma unroll
    for (int mb = 0; mb < 4; mb++) {
        #pragma unroll
        for (int nb = 0; nb < NB; nb++) {
            const int row  = m0 + wm + mb * 16 + quad * 4;   // token base, +r
            const int col  = n0 + wn + nb * 16 + l16;
            if (MODE == 1) {
                #pragma unroll
                for (int r = 0; r < 4; r++)
                    Cf[(size_t)(row + r) * 1024 + col] = acc[mb][nb][r] + bias[col];
            } else {
                const int region = col >> 10;         // uniform per block
                const int ccol = col & 1023;
                const int bb = row >> 11, srow = row & 2047;
                const int kt = srow >> 6;
                const int hh = ccol >> 6, dd = ccol & 63;
                if (region == 0) {
                    #pragma unroll
                    for (int r = 0; r < 4; r++)
                        Cq[(size_t)(row + r) * 1024 + ccol] =
                            f2bf(acc[mb][nb][r] * 0.18033688011112042f);
                } else if (region == 1) {
                    const int t = dd >> 4, hik = (dd >> 3) & 1, j = dd & 7;
                    #pragma unroll
                    for (int r = 0; r < 4; r++) {
                        const int km = (srow + r) & 63;
                        const int kn = km >> 5, l31k = km & 31;
                        const int lanek = hik * 32 + l31k;
                        Kfr[((((size_t)(bb * 16 + hh) * 32 + kt) * 8 + kn * 4 + t) * 64
                             + lanek) * 8 + j] = f2bf(acc[mb][nb][r]);
                    }
                } else {
                    const int kinb = srow & 63;               // +r stays in {t,hiv}
                    const int t = kinb >> 4, hiv = (kinb >> 3) & 1, jb = kinb & 7;
                    const int nd = dd >> 5, l31v = dd & 31;
                    const int lanev = hiv * 32 + l31v;
                    ushort4 pk;
                    pk.x = f2bf(acc[mb][nb][0]); pk.y = f2bf(acc[mb][nb][1]);
                    pk.z = f2bf(acc[mb][nb][2]); pk.w = f2bf(acc[mb][nb][3]);
                    *(ushort4*)&Vfr[((((size_t)(bb * 16 + hh) * 32 + kt) * 8 + nd * 4 + t) * 64
                                     + lanev) * 8 + jb] = pk;
                }
            }
        }
    }
}

// ---------------------------------------------------------------------------
// Kernel 4: masked attention, 32x32x16 MFMA, barrier-free.
// Wave owns 32 q-rows; block = 4 waves = 128 q-rows; grid (16,16,2)=512.
// K/V B-frags loaded DIRECTLY from frag-swizzled global (coalesced, L1/L2-hot).
// LDS only for the per-wave P round-trip (C-layout write -> A-layout read).
// Softmax: no online max (Q pre-scaled by 0.125*log2e, exp2, mask-as-zero),
// row sums via MFMA with ones B-frag.
// C/D 32x32 layout: col=lane&31, row=(reg&3)+8*(reg>>2)+4*(lane>>5).
// A 32x32x16 layout: m=lane&31, k=(lane>>5)*8+j; B mirrors with n=lane&31.
// ---------------------------------------------------------------------------
__global__ __launch_bounds__(256, 2) void attn_kernel(
    const u16* __restrict__ Qg, const u16* __restrict__ Kfr, const u16* __restrict__ Vfr,
    const u64* __restrict__ Mb2, u16* __restrict__ AO)
{
    constexpr int LDP = 72;
    const int qt = blockIdx.x;      // 0..15
    const int h  = blockIdx.y;      // 0..15
    const int b  = blockIdx.z;      // 0..1
    const int tid = threadIdx.x, wave = tid >> 6, lane = tid & 63;
    const int l31 = lane & 31, hi = lane >> 5;

    __shared__ u16 Psh[4][32 * LDP];           // 18.4 KB total

    const int    qrow0 = qt * 128 + wave * 32;
    const size_t tok   = (size_t)b * 2048;
    const int    bh    = b * 16 + h;

    // Q A-frags (pre-scaled by 0.125*log2e): qf[t] covers d = t*16 + hi*8 + j
    bf16x8 qf[4];
    {
        const u16* qp = Qg + (tok + qrow0 + l31) * 1024 + h * 64 + hi * 8;
        #pragma unroll
        for (int t = 0; t < 4; t++) qf[t] = *(const bf16x8*)(qp + t * 16);
    }
    bf16x8 ones;
    #pragma unroll
    for (int j = 0; j < 8; j++) ones[j] = (short)0x3F80;   // bf16 1.0

    f32x16 oacc0, oacc1, lacc;
    #pragma unroll
    for (int i = 0; i < 16; i++) { oacc0[i] = 0.f; oacc1[i] = 0.f; lacc[i] = 0.f; }

    const u16* kfp = Kfr + ((size_t)bh * 256) * 512 + lane * 8;   // + (kt*8+f)*512
    const u16* vfp = Vfr + ((size_t)bh * 256) * 512 + lane * 8;

    u16* psw = &Psh[wave][0];

    #pragma unroll 1
    for (int kt = 0; kt < 32; kt++) {
        // frag loads (coalesced 1KB each, L1-shared across the block's waves)
        bf16x8 kf[8], vf[8];
        #pragma unroll
        for (int f = 0; f < 8; f++) {
            kf[f] = *(const bf16x8*)(kfp + (size_t)(kt * 8 + f) * 512);
            vf[f] = *(const bf16x8*)(vfp + (size_t)(kt * 8 + f) * 512);
        }

        // S = Q K^T : two 32x32 tiles (kn = key half)
        f32x16 s0, s1;
        #pragma unroll
        for (int i = 0; i < 16; i++) { s0[i] = 0.f; s1[i] = 0.f; }
        #pragma unroll
        for (int t = 0; t < 4; t++)
            s0 = __builtin_amdgcn_mfma_f32_32x32x16_bf16(qf[t], kf[t], s0, 0, 0, 0);
        #pragma unroll
        for (int t = 0; t < 4; t++)
            s1 = __builtin_amdgcn_mfma_f32_32x32x16_bf16(qf[t], kf[4 + t], s1, 0, 0, 0);

        // exp2 + mask (bitmask, transposed layout) -> Psh (C-layout write)
        const u64* mptr = Mb2 + ((size_t)(b * 32 + kt)) * 2048 + qrow0 + hi * 4;
        #pragma unroll
        for (int g = 0; g < 4; g++) {
            uint4 ma  = *(const uint4*)(mptr + g * 8);        // rows g*8+hi*4 +0,+1
            uint4 mb_ = *(const uint4*)(mptr + g * 8 + 2);    // rows +2,+3
            #pragma unroll
            for (int rr = 0; rr < 4; rr++) {
                const u32 wx = rr == 0 ? ma.x : rr == 1 ? ma.z : rr == 2 ? mb_.x : mb_.z;
                const u32 wy = rr == 0 ? ma.y : rr == 1 ? ma.w : rr == 2 ? mb_.y : mb_.w;
                const int reg = g * 4 + rr;
                const int row = g * 8 + hi * 4 + rr;
                float e0 = __builtin_amdgcn_exp2f(s0[reg]);
                float e1 = __builtin_amdgcn_exp2f(s1[reg]);
                e0 = ((wx >> l31) & 1u) ? e0 : 0.0f;
                e1 = ((wy >> l31) & 1u) ? e1 : 0.0f;
                psw[row * LDP + l31]      = (u16)(__float_as_uint(e0) >> 16);
                psw[row * LDP + 32 + l31] = (u16)(__float_as_uint(e1) >> 16);
            }
        }

        // P A-frags (same-wave LDS round-trip; hw waitcnt orders it)
        bf16x8 pa[4];
        #pragma unroll
        for (int t = 0; t < 4; t++)
            pa[t] = *(const bf16x8*)&psw[l31 * LDP + t * 16 + hi * 8];

        // row sums + O += P V
        #pragma unroll
        for (int t = 0; t < 4; t++)
            lacc = __builtin_amdgcn_mfma_f32_32x32x16_bf16(pa[t], ones, lacc, 0, 0, 0);
        #pragma unroll
        for (int t = 0; t < 4; t++)
            oacc0 = __builtin_amdgcn_mfma_f32_32x32x16_bf16(pa[t], vf[t], oacc0, 0, 0, 0);
        #pragma unroll
        for (int t = 0; t < 4; t++)
            oacc1 = __builtin_amdgcn_mfma_f32_32x32x16_bf16(pa[t], vf[4 + t], oacc1, 0, 0, 0);
    }

    // normalize + store: AO[token][h*64 + d] bf16
    #pragma unroll
    for (int reg = 0; reg < 16; reg++) {
        const int row = (reg >> 2) * 8 + hi * 4 + (reg & 3);
        const float inv = 1.0f / lacc[reg];
        const size_t base = (tok + qrow0 + row) * 1024 + h * 64;
        AO[base + l31]      = f2bf(oacc0[reg] * inv);
        AO[base + 32 + l31] = f2bf(oacc1[reg] * inv);
    }
}

// ---------------------------------------------------------------------------
extern "C" void kernel_launch(void* const* d_in, const int* in_sizes, int n_in,
                              void* d_out, int out_size, void* d_ws, size_t ws_size,
                              hipStream_t stream)
{
    const float* x  = (const float*)d_in[0];
    const int*   Mm = (const int*)d_in[1];
    const float* Wq = (const float*)d_in[2];
    const float* Wk = (const float*)d_in[3];
    const float* Wv = (const float*)d_in[4];
    const float* Wo = (const float*)d_in[5];
    const float* bo = (const float*)d_in[6];
    float* out = (float*)d_out;

    // workspace layout (u16 elements), ~49 MB total
    u16* ws  = (u16*)d_ws;
    u16* xb  = ws;                 // 4194304
    u16* wqb = xb  + 4194304;      // 1048576 (wq|wk|wv contiguous = 3072x1024)
    u16* wkb = wqb + 1048576;
    u16* wvb = wkb + 1048576;
    u16* wob = wvb + 1048576;
    u16* Qb  = wob + 1048576;      // 4194304 (pre-scaled by 0.125*log2e)
    u16* Kfr = Qb  + 4194304;      // 4194304 frag-swizzled K
    u16* Vfr = Kfr + 4194304;      // 4194304 frag-swizzled V
    u16* AOb = Vfr + 4194304;      // 4194304
    u64* Mb2 = (u64*)(AOb + 4194304);  // 131072 u64 = 1 MB, transposed

    cvt_kernel<<<8192, 256, 0, stream>>>(
        (const float4*)x, (const float4*)Wq, (const float4*)Wk,
        (const float4*)Wv, (const float4*)Wo, xb, wqb, wkb, wvb, wob);

    pack_mask<<<32768, 256, 0, stream>>>(Mm, Mb2);

    dim3 g1(24, 32, 1);  // N=3072/128, M=4096/128 — fused QKV
    gemm_k<0, 128><<<g1, 256, 0, stream>>>(xb, wqb, Qb, Kfr, Vfr, nullptr, nullptr);

    dim3 g2(16, 16, 2);  // S/128, H, B
    attn_kernel<<<g2, 256, 0, stream>>>(Qb, Kfr, Vfr, Mb2, AOb);

    dim3 g3(16, 32, 1);  // N/64, M/128 — 512 blocks
    gemm_k<1, 64><<<g3, 256, 0, stream>>>(AOb, wob, nullptr, nullptr, nullptr,
                                          out, bo);
}